// Round 17
// baseline (681.947 us; speedup 1.0000x reference)
//
#include <hip/hip_runtime.h>
#include <hip/hip_bf16.h>

#define B_ROWS   524288
#define MEL_BINS 128
#define DIM      64
#define KCODES   128

typedef float v2f __attribute__((ext_vector_type(2)));
struct V2P { v2f lo, hi; };

// packed fp32 FMA: two INDEPENDENT IEEE f32 FMAs per instruction (CDNA2+,
// R8-proven on gfx950). Pairing is across independent chains only; each
// component's op order is bit-identical to scalar fmaf.
#define PK(A, C, Z) asm("v_pk_fma_f32 %0, %1, %2, %0" : "+v"(A) : "v"(C), "v"(Z))

// ---------------- workspace layout (floats) ----------------
// WT [128*64]  : W_in^T, WT[j*64+d] = W_in[d*128+j]
// P0 [8*1024]  : cb0 16-k panels, P0[c*1024 + d*16 + t] = cb0[(c*16+t)*64 + d]
// P1 [8*1024]  : cb1 panels
// n0,n1 [128]  : np pairwise ||c_k||^2
// T0,T1 [128*128] : cb @ W_out^T
#define WS_WT 0
#define WS_P0 (WS_WT + MEL_BINS*DIM)        // 8192
#define WS_P1 (WS_P0 + DIM*KCODES)          // 16384
#define WS_N0 (WS_P1 + DIM*KCODES)          // 24576
#define WS_N1 (WS_N0 + KCODES)              // 24704
#define WS_T0 (WS_N1 + KCODES)              // 24832
#define WS_T1 (WS_T0 + KCODES*MEL_BINS)     // 41216
#define WS_TOT (WS_T1 + KCODES*MEL_BINS)    // 57600 floats

// numpy pairwise_sum (scalar path) emulation for n=64 of v[d]*v[d].
__device__ __forceinline__ float np_pairwise64_sq(const float* v) {
#pragma clang fp contract(off)
    float r0 = v[0]*v[0], r1 = v[1]*v[1], r2 = v[2]*v[2], r3 = v[3]*v[3];
    float r4 = v[4]*v[4], r5 = v[5]*v[5], r6 = v[6]*v[6], r7 = v[7]*v[7];
#pragma unroll
    for (int i = 8; i < 64; i += 8) {
        r0 += v[i+0]*v[i+0]; r1 += v[i+1]*v[i+1];
        r2 += v[i+2]*v[i+2]; r3 += v[i+3]*v[i+3];
        r4 += v[i+4]*v[i+4]; r5 += v[i+5]*v[i+5];
        r6 += v[i+6]*v[i+6]; r7 += v[i+7]*v[i+7];
    }
    return ((r0 + r1) + (r2 + r3)) + ((r4 + r5) + (r6 + r7));
}

__global__ __launch_bounds__(256) void rvq_precomp(
    const float* __restrict__ W_in, const float* __restrict__ cb0,
    const float* __restrict__ cb1, const float* __restrict__ W_out,
    float* __restrict__ ws)
{
#pragma clang fp contract(off)
    float* WT = ws + WS_WT;
    float* P0 = ws + WS_P0;
    float* P1 = ws + WS_P1;
    float* n0 = ws + WS_N0;
    float* n1 = ws + WS_N1;
    float* T0 = ws + WS_T0;
    float* T1 = ws + WS_T1;

    int tid = blockIdx.x * 256 + threadIdx.x;
    if (tid < 16384) {                       // T0[i][m] (mel path: loose threshold)
        int i = tid >> 7, m = tid & 127;
        double a = 0.0;
        for (int d = 0; d < DIM; ++d)
            a = fma((double)cb0[i*DIM + d], (double)W_out[m*DIM + d], a);
        T0[tid] = (float)a;
    } else if (tid < 32768) {                // T1[i][m]
        int t = tid - 16384;
        int i = t >> 7, m = t & 127;
        double a = 0.0;
        for (int d = 0; d < DIM; ++d)
            a = fma((double)cb1[i*DIM + d], (double)W_out[m*DIM + d], a);
        T1[t] = (float)a;
    } else if (tid < 40960) {                // WT[j][d] = W_in[d][j]
        int t = tid - 32768;
        int j = t >> 6, d = t & 63;
        WT[t] = W_in[d*MEL_BINS + j];
    } else if (tid < 41216) {                // n0 / n1 (exact np pairwise)
        int t = tid - 40960;
        const float* cb = (t & 128) ? cb1 : cb0;
        float*       nn = (t & 128) ? n1  : n0;
        int k = t & 127;
        nn[k] = np_pairwise64_sq(cb + k*DIM);
    } else if (tid < 49408) {                // P0 panels
        int e = tid - 41216;
        int c = e >> 10, rem = e & 1023;
        int d = rem >> 4, t = rem & 15;
        P0[e] = cb0[(c*16 + t)*DIM + d];
    } else if (tid < 57600) {                // P1 panels
        int e = tid - 49408;
        int c = e >> 10, rem = e & 1023;
        int d = rem >> 4, t = rem & 15;
        P1[e] = cb1[(c*16 + t)*DIM + d];
    }
}

// 1 row/thread. R16 structure (16 KB staged LDS, uniform ds_read_b128
// broadcasts, d-outer ILP dot loops) with v_pk_fma_f32 packing across
// INDEPENDENT chains (k-pairs in dots, d-pairs in z-GEMM). All packed FMAs
// are exact IEEE f32; PER-VALUE FP OP ORDER IS BIT-IDENTICAL to the
// R3-verified np-f32 emulation. DO NOT REORDER.
__global__ __launch_bounds__(256) void rvq_main(
    const float* __restrict__ mel,
    const float* __restrict__ b_in,
    const float* __restrict__ cb0,
    const float* __restrict__ cb1,
    const float* __restrict__ b_out,
    const float* __restrict__ ws,
    float* __restrict__ out_mel,
    float* __restrict__ out_idx)
{
#pragma clang fp contract(off)
    const float* __restrict__ n0g = ws + WS_N0;
    const float* __restrict__ n1g = ws + WS_N1;
    const float* __restrict__ T0  = ws + WS_T0;
    const float* __restrict__ T1  = ws + WS_T1;

    __shared__ float slds[4096];             // 16 KB staging buffer
    float4* sw4 = reinterpret_cast<float4*>(slds);
    const float4* sl4 = reinterpret_cast<const float4*>(slds);

    const int tid = threadIdx.x;
    const int b = blockIdx.x * 256 + tid;
    const float4* melr = reinterpret_cast<const float4*>(mel + (size_t)b * MEL_BINS);

    v2f zp[32];                              // z as 32 independent (d,d+1) pairs
#pragma unroll
    for (int i = 0; i < 32; ++i) zp[i] = (v2f){0.f, 0.f};

    // ======== z-GEMM in two j-halves (WT staged 16 KB at a time) ========
    const float4* wt4 = reinterpret_cast<const float4*>(ws + WS_WT);
    for (int h = 0; h < 2; ++h) {
        __syncthreads();
#pragma unroll
        for (int i = 0; i < 4; ++i) sw4[i*256 + tid] = wt4[h*1024 + i*256 + tid];
        __syncthreads();

        for (int jc = 0; jc < 16; ++jc) {    // global j = (h*16+jc)*4 + seg, ascending
            float4 m4 = melr[h*16 + jc];
#pragma unroll
            for (int seg = 0; seg < 4; ++seg) {
                float mj = (seg == 0) ? m4.x : (seg == 1) ? m4.y : (seg == 2) ? m4.z : m4.w;
                v2f mj2 = (v2f){mj, mj};
                const float4* w4 = sl4 + (jc*4 + seg)*16;   // uniform -> broadcast
#pragma unroll
                for (int q = 0; q < 16; ++q) {
                    V2P wv = __builtin_bit_cast(V2P, w4[q]);
                    PK(zp[2*q + 0], wv.lo, mj2);   // z[4q],z[4q+1]   indep chains
                    PK(zp[2*q + 1], wv.hi, mj2);   // z[4q+2],z[4q+3]
                }
            }
        }
    }

    // ---- extract scalars (register aliasing, no FP ops), frozen bias add ----
    float z[DIM];
#pragma unroll
    for (int i = 0; i < 32; ++i) { z[2*i] = zp[i].x; z[2*i + 1] = zp[i].y; }
#pragma unroll
    for (int d = 0; d < DIM; ++d) z[d] = z[d] + b_in[d];

    // ---- sum_rr (np pairwise, frozen) ----
    float s0 = z[0]*z[0], s1 = z[1]*z[1], s2 = z[2]*z[2], s3 = z[3]*z[3];
    float s4 = z[4]*z[4], s5 = z[5]*z[5], s6 = z[6]*z[6], s7 = z[7]*z[7];
#pragma unroll
    for (int i = 8; i < 64; i += 8) {
        s0 += z[i+0]*z[i+0]; s1 += z[i+1]*z[i+1];
        s2 += z[i+2]*z[i+2]; s3 += z[i+3]*z[i+3];
        s4 += z[i+4]*z[i+4]; s5 += z[i+5]*z[i+5];
        s6 += z[i+6]*z[i+6]; s7 += z[i+7]*z[i+7];
    }
    float sum_rr = ((s0 + s1) + (s2 + s3)) + ((s4 + s5) + (s6 + s7));

    // ======== codebook 0: k-halves staged, chunks of 16 k, packed ILP ========
    const float4* p04 = reinterpret_cast<const float4*>(ws + WS_P0);
    float best0 = 3.4e38f; int i0 = 0;
    for (int h = 0; h < 2; ++h) {
        __syncthreads();
#pragma unroll
        for (int i = 0; i < 4; ++i) sw4[i*256 + tid] = p04[h*1024 + i*256 + tid];
        __syncthreads();

        for (int q = 0; q < 4; ++q) {        // chunk: k = h*64 + q*16 + t
            const float4* pan = sl4 + q*256;
            v2f av[8];                       // 8 k-pairs, 16 indep chains
#pragma unroll
            for (int t = 0; t < 8; ++t) av[t] = (v2f){0.f, 0.f};
#pragma unroll
            for (int d = 0; d < DIM; ++d) {  // each k: single acc, ascending d ✓
                V2P P0 = __builtin_bit_cast(V2P, pan[d*4 + 0]);
                V2P P1 = __builtin_bit_cast(V2P, pan[d*4 + 1]);
                V2P P2 = __builtin_bit_cast(V2P, pan[d*4 + 2]);
                V2P P3 = __builtin_bit_cast(V2P, pan[d*4 + 3]);
                float zd = z[d];
                v2f zd2 = (v2f){zd, zd};
                PK(av[0], P0.lo, zd2); PK(av[1], P0.hi, zd2);
                PK(av[2], P1.lo, zd2); PK(av[3], P1.hi, zd2);
                PK(av[4], P2.lo, zd2); PK(av[5], P2.hi, zd2);
                PK(av[6], P3.lo, zd2); PK(av[7], P3.hi, zd2);
            }
            const int kb = h*64 + q*16;
            const float* nk = n0g + kb;
#pragma unroll
            for (int j = 0; j < 8; ++j) {    // ascending k, strict < (np.argmin)
                float d0 = (sum_rr - 2.0f*av[j].x) + nk[2*j + 0];
                float d1 = (sum_rr - 2.0f*av[j].y) + nk[2*j + 1];
                if (d0 < best0) { best0 = d0; i0 = kb + 2*j + 0; }
                if (d1 < best0) { best0 = d1; i0 = kb + 2*j + 1; }
            }
        }
    }

    // ---- residual = z - cb0[i0] : per-lane global gather (L2-hot), frozen sub
    {
        const float* cc = cb0 + (size_t)i0 * DIM;
#pragma unroll
        for (int d = 0; d < DIM; ++d) z[d] = z[d] - cc[d];
    }

    // ---- sum_rr' (np pairwise, frozen) ----
    s0 = z[0]*z[0]; s1 = z[1]*z[1]; s2 = z[2]*z[2]; s3 = z[3]*z[3];
    s4 = z[4]*z[4]; s5 = z[5]*z[5]; s6 = z[6]*z[6]; s7 = z[7]*z[7];
#pragma unroll
    for (int i = 8; i < 64; i += 8) {
        s0 += z[i+0]*z[i+0]; s1 += z[i+1]*z[i+1];
        s2 += z[i+2]*z[i+2]; s3 += z[i+3]*z[i+3];
        s4 += z[i+4]*z[i+4]; s5 += z[i+5]*z[i+5];
        s6 += z[i+6]*z[i+6]; s7 += z[i+7]*z[i+7];
    }
    sum_rr = ((s0 + s1) + (s2 + s3)) + ((s4 + s5) + (s6 + s7));

    // ======== codebook 1 ========
    const float4* p14 = reinterpret_cast<const float4*>(ws + WS_P1);
    float best1 = 3.4e38f; int i1 = 0;
    for (int h = 0; h < 2; ++h) {
        __syncthreads();
#pragma unroll
        for (int i = 0; i < 4; ++i) sw4[i*256 + tid] = p14[h*1024 + i*256 + tid];
        __syncthreads();

        for (int q = 0; q < 4; ++q) {
            const float4* pan = sl4 + q*256;
            v2f av[8];
#pragma unroll
            for (int t = 0; t < 8; ++t) av[t] = (v2f){0.f, 0.f};
#pragma unroll
            for (int d = 0; d < DIM; ++d) {
                V2P P0 = __builtin_bit_cast(V2P, pan[d*4 + 0]);
                V2P P1 = __builtin_bit_cast(V2P, pan[d*4 + 1]);
                V2P P2 = __builtin_bit_cast(V2P, pan[d*4 + 2]);
                V2P P3 = __builtin_bit_cast(V2P, pan[d*4 + 3]);
                float zd = z[d];
                v2f zd2 = (v2f){zd, zd};
                PK(av[0], P0.lo, zd2); PK(av[1], P0.hi, zd2);
                PK(av[2], P1.lo, zd2); PK(av[3], P1.hi, zd2);
                PK(av[4], P2.lo, zd2); PK(av[5], P2.hi, zd2);
                PK(av[6], P3.lo, zd2); PK(av[7], P3.hi, zd2);
            }
            const int kb = h*64 + q*16;
            const float* nk = n1g + kb;
#pragma unroll
            for (int j = 0; j < 8; ++j) {
                float d0 = (sum_rr - 2.0f*av[j].x) + nk[2*j + 0];
                float d1 = (sum_rr - 2.0f*av[j].y) + nk[2*j + 1];
                if (d0 < best1) { best1 = d0; i1 = kb + 2*j + 0; }
                if (d1 < best1) { best1 = d1; i1 = kb + 2*j + 1; }
            }
        }
    }

    // ---- decode: out = T0[i0] + T1[i1] + b_out ----
    const float4* t0r = reinterpret_cast<const float4*>(T0 + (size_t)i0 * MEL_BINS);
    const float4* t1r = reinterpret_cast<const float4*>(T1 + (size_t)i1 * MEL_BINS);
    float4* outr = reinterpret_cast<float4*>(out_mel + (size_t)b * MEL_BINS);
#pragma unroll 4
    for (int q = 0; q < MEL_BINS / 4; ++q) {
        float4 a = t0r[q], cc = t1r[q];
        float4 o;
        o.x = a.x + cc.x + b_out[4*q + 0];
        o.y = a.y + cc.y + b_out[4*q + 1];
        o.z = a.z + cc.z + b_out[4*q + 2];
        o.w = a.w + cc.w + b_out[4*q + 3];
        outr[q] = o;
    }

    out_idx[2*(size_t)b + 0] = (float)i0;
    out_idx[2*(size_t)b + 1] = (float)i1;
}

extern "C" void kernel_launch(void* const* d_in, const int* in_sizes, int n_in,
                              void* d_out, int out_size, void* d_ws, size_t ws_size,
                              hipStream_t stream)
{
    const float* mel   = (const float*)d_in[0];
    const float* W_in  = (const float*)d_in[1];
    const float* b_in  = (const float*)d_in[2];
    const float* cb0   = (const float*)d_in[3];
    const float* cb1   = (const float*)d_in[4];
    const float* W_out = (const float*)d_in[5];
    const float* b_out = (const float*)d_in[6];

    float* ws      = (float*)d_ws;                 // 230400 bytes used
    float* out_mel = (float*)d_out;
    float* out_idx = (float*)d_out + (size_t)B_ROWS * MEL_BINS;

    rvq_precomp<<<(WS_TOT + 255) / 256, 256, 0, stream>>>(W_in, cb0, cb1, W_out, ws);
    rvq_main<<<B_ROWS / 256, 256, 0, stream>>>(mel, b_in, cb0, cb1, b_out, ws,
                                               out_mel, out_idx);
}

// Round 18
// 672.157 us; speedup vs baseline: 1.0146x; 1.0146x over previous
//
#include <hip/hip_runtime.h>
#include <hip/hip_bf16.h>

#define B_ROWS   524288
#define MEL_BINS 128
#define DIM      64
#define KCODES   128

typedef float v2f __attribute__((ext_vector_type(2)));
struct V2P { v2f lo, hi; };

// compiler-native packed fp32 FMA: lowers to v_pk_fma_f32 on gfx950 (no
// inline asm -> scheduler + AGPR allocation stay free). Each component is
// an exact IEEE f32 fma; pairing is across INDEPENDENT chains only.
#define PKF(A, C, Z) (A) = __builtin_elementwise_fma((C), (Z), (A))

// ---------------- workspace layout (floats) ----------------
// WT [128*64]  : W_in^T, WT[j*64+d] = W_in[d*128+j]
// P0 [8*1024]  : cb0 16-k panels, P0[c*1024 + d*16 + t] = cb0[(c*16+t)*64 + d]
// P1 [8*1024]  : cb1 panels
// n0,n1 [128]  : np pairwise ||c_k||^2
// T0,T1 [128*128] : cb @ W_out^T
#define WS_WT 0
#define WS_P0 (WS_WT + MEL_BINS*DIM)        // 8192
#define WS_P1 (WS_P0 + DIM*KCODES)          // 16384
#define WS_N0 (WS_P1 + DIM*KCODES)          // 24576
#define WS_N1 (WS_N0 + KCODES)              // 24704
#define WS_T0 (WS_N1 + KCODES)              // 24832
#define WS_T1 (WS_T0 + KCODES*MEL_BINS)     // 41216
#define WS_TOT (WS_T1 + KCODES*MEL_BINS)    // 57600 floats

// numpy pairwise_sum (scalar path) emulation for n=64 of v[d]*v[d].
__device__ __forceinline__ float np_pairwise64_sq(const float* v) {
#pragma clang fp contract(off)
    float r0 = v[0]*v[0], r1 = v[1]*v[1], r2 = v[2]*v[2], r3 = v[3]*v[3];
    float r4 = v[4]*v[4], r5 = v[5]*v[5], r6 = v[6]*v[6], r7 = v[7]*v[7];
#pragma unroll
    for (int i = 8; i < 64; i += 8) {
        r0 += v[i+0]*v[i+0]; r1 += v[i+1]*v[i+1];
        r2 += v[i+2]*v[i+2]; r3 += v[i+3]*v[i+3];
        r4 += v[i+4]*v[i+4]; r5 += v[i+5]*v[i+5];
        r6 += v[i+6]*v[i+6]; r7 += v[i+7]*v[i+7];
    }
    return ((r0 + r1) + (r2 + r3)) + ((r4 + r5) + (r6 + r7));
}

__global__ __launch_bounds__(256) void rvq_precomp(
    const float* __restrict__ W_in, const float* __restrict__ cb0,
    const float* __restrict__ cb1, const float* __restrict__ W_out,
    float* __restrict__ ws)
{
#pragma clang fp contract(off)
    float* WT = ws + WS_WT;
    float* P0 = ws + WS_P0;
    float* P1 = ws + WS_P1;
    float* n0 = ws + WS_N0;
    float* n1 = ws + WS_N1;
    float* T0 = ws + WS_T0;
    float* T1 = ws + WS_T1;

    int tid = blockIdx.x * 256 + threadIdx.x;
    if (tid < 16384) {                       // T0[i][m] (mel path: loose threshold)
        int i = tid >> 7, m = tid & 127;
        double a = 0.0;
        for (int d = 0; d < DIM; ++d)
            a = fma((double)cb0[i*DIM + d], (double)W_out[m*DIM + d], a);
        T0[tid] = (float)a;
    } else if (tid < 32768) {                // T1[i][m]
        int t = tid - 16384;
        int i = t >> 7, m = t & 127;
        double a = 0.0;
        for (int d = 0; d < DIM; ++d)
            a = fma((double)cb1[i*DIM + d], (double)W_out[m*DIM + d], a);
        T1[t] = (float)a;
    } else if (tid < 40960) {                // WT[j][d] = W_in[d][j]
        int t = tid - 32768;
        int j = t >> 6, d = t & 63;
        WT[t] = W_in[d*MEL_BINS + j];
    } else if (tid < 41216) {                // n0 / n1 (exact np pairwise)
        int t = tid - 40960;
        const float* cb = (t & 128) ? cb1 : cb0;
        float*       nn = (t & 128) ? n1  : n0;
        int k = t & 127;
        nn[k] = np_pairwise64_sq(cb + k*DIM);
    } else if (tid < 49408) {                // P0 panels
        int e = tid - 41216;
        int c = e >> 10, rem = e & 1023;
        int d = rem >> 4, t = rem & 15;
        P0[e] = cb0[(c*16 + t)*DIM + d];
    } else if (tid < 57600) {                // P1 panels
        int e = tid - 49408;
        int c = e >> 10, rem = e & 1023;
        int d = rem >> 4, t = rem & 15;
        P1[e] = cb1[(c*16 + t)*DIM + d];
    }
}

// 1 row/thread. R16 structure (16 KB staged LDS, uniform ds_read_b128
// broadcasts, d-outer ILP dot loops) with compiler-native v2f packed FMA
// across INDEPENDENT chains (d-pairs in z-GEMM, k-pairs in dots).
// PER-VALUE FP OP ORDER IS BIT-IDENTICAL to the R3-verified np-f32
// emulation. DO NOT REORDER.
__global__ __launch_bounds__(256) void rvq_main(
    const float* __restrict__ mel,
    const float* __restrict__ b_in,
    const float* __restrict__ cb0,
    const float* __restrict__ cb1,
    const float* __restrict__ b_out,
    const float* __restrict__ ws,
    float* __restrict__ out_mel,
    float* __restrict__ out_idx)
{
#pragma clang fp contract(off)
    const float* __restrict__ n0g = ws + WS_N0;
    const float* __restrict__ n1g = ws + WS_N1;
    const float* __restrict__ T0  = ws + WS_T0;
    const float* __restrict__ T1  = ws + WS_T1;

    __shared__ float slds[4096];             // 16 KB staging buffer
    float4* sw4 = reinterpret_cast<float4*>(slds);
    const float4* sl4 = reinterpret_cast<const float4*>(slds);

    const int tid = threadIdx.x;
    const int b = blockIdx.x * 256 + tid;
    const float4* melr = reinterpret_cast<const float4*>(mel + (size_t)b * MEL_BINS);

    v2f zp[32];                              // z as 32 independent (d,d+1) pairs
#pragma unroll
    for (int i = 0; i < 32; ++i) zp[i] = (v2f){0.f, 0.f};

    // ======== z-GEMM in two j-halves (WT staged 16 KB at a time) ========
    const float4* wt4 = reinterpret_cast<const float4*>(ws + WS_WT);
    for (int h = 0; h < 2; ++h) {
        __syncthreads();
#pragma unroll
        for (int i = 0; i < 4; ++i) sw4[i*256 + tid] = wt4[h*1024 + i*256 + tid];
        __syncthreads();

        for (int jc = 0; jc < 16; ++jc) {    // global j = (h*16+jc)*4 + seg, ascending
            float4 m4 = melr[h*16 + jc];
#pragma unroll
            for (int seg = 0; seg < 4; ++seg) {
                float mj = (seg == 0) ? m4.x : (seg == 1) ? m4.y : (seg == 2) ? m4.z : m4.w;
                v2f mj2 = (v2f){mj, mj};
                const float4* w4 = sl4 + (jc*4 + seg)*16;   // uniform -> broadcast
#pragma unroll
                for (int q = 0; q < 16; ++q) {
                    V2P wv = __builtin_bit_cast(V2P, w4[q]);
                    PKF(zp[2*q + 0], wv.lo, mj2);   // z[4q],z[4q+1]   indep chains
                    PKF(zp[2*q + 1], wv.hi, mj2);   // z[4q+2],z[4q+3]
                }
            }
        }
    }

    // ---- extract scalars (register aliasing, no FP ops), frozen bias add ----
    float z[DIM];
#pragma unroll
    for (int i = 0; i < 32; ++i) { z[2*i] = zp[i].x; z[2*i + 1] = zp[i].y; }
#pragma unroll
    for (int d = 0; d < DIM; ++d) z[d] = z[d] + b_in[d];

    // ---- sum_rr (np pairwise, frozen) ----
    float s0 = z[0]*z[0], s1 = z[1]*z[1], s2 = z[2]*z[2], s3 = z[3]*z[3];
    float s4 = z[4]*z[4], s5 = z[5]*z[5], s6 = z[6]*z[6], s7 = z[7]*z[7];
#pragma unroll
    for (int i = 8; i < 64; i += 8) {
        s0 += z[i+0]*z[i+0]; s1 += z[i+1]*z[i+1];
        s2 += z[i+2]*z[i+2]; s3 += z[i+3]*z[i+3];
        s4 += z[i+4]*z[i+4]; s5 += z[i+5]*z[i+5];
        s6 += z[i+6]*z[i+6]; s7 += z[i+7]*z[i+7];
    }
    float sum_rr = ((s0 + s1) + (s2 + s3)) + ((s4 + s5) + (s6 + s7));

    // ======== codebook 0: k-halves staged, chunks of 16 k, packed ILP ========
    const float4* p04 = reinterpret_cast<const float4*>(ws + WS_P0);
    float best0 = 3.4e38f; int i0 = 0;
    for (int h = 0; h < 2; ++h) {
        __syncthreads();
#pragma unroll
        for (int i = 0; i < 4; ++i) sw4[i*256 + tid] = p04[h*1024 + i*256 + tid];
        __syncthreads();

        for (int q = 0; q < 4; ++q) {        // chunk: k = h*64 + q*16 + t
            const float4* pan = sl4 + q*256;
            v2f av[8];                       // 8 k-pairs, 16 indep chains
#pragma unroll
            for (int t = 0; t < 8; ++t) av[t] = (v2f){0.f, 0.f};
#pragma unroll
            for (int d = 0; d < DIM; ++d) {  // each k: single acc, ascending d ✓
                V2P P0 = __builtin_bit_cast(V2P, pan[d*4 + 0]);
                V2P P1 = __builtin_bit_cast(V2P, pan[d*4 + 1]);
                V2P P2 = __builtin_bit_cast(V2P, pan[d*4 + 2]);
                V2P P3 = __builtin_bit_cast(V2P, pan[d*4 + 3]);
                float zd = z[d];
                v2f zd2 = (v2f){zd, zd};
                PKF(av[0], P0.lo, zd2); PKF(av[1], P0.hi, zd2);
                PKF(av[2], P1.lo, zd2); PKF(av[3], P1.hi, zd2);
                PKF(av[4], P2.lo, zd2); PKF(av[5], P2.hi, zd2);
                PKF(av[6], P3.lo, zd2); PKF(av[7], P3.hi, zd2);
            }
            const int kb = h*64 + q*16;
            const float* nk = n0g + kb;
#pragma unroll
            for (int j = 0; j < 8; ++j) {    // ascending k, strict < (np.argmin)
                float d0 = (sum_rr - 2.0f*av[j].x) + nk[2*j + 0];
                float d1 = (sum_rr - 2.0f*av[j].y) + nk[2*j + 1];
                if (d0 < best0) { best0 = d0; i0 = kb + 2*j + 0; }
                if (d1 < best0) { best0 = d1; i0 = kb + 2*j + 1; }
            }
        }
    }

    // ---- residual = z - cb0[i0] : per-lane global gather (L2-hot), frozen sub
    {
        const float* cc = cb0 + (size_t)i0 * DIM;
#pragma unroll
        for (int d = 0; d < DIM; ++d) z[d] = z[d] - cc[d];
    }

    // ---- sum_rr' (np pairwise, frozen) ----
    s0 = z[0]*z[0]; s1 = z[1]*z[1]; s2 = z[2]*z[2]; s3 = z[3]*z[3];
    s4 = z[4]*z[4]; s5 = z[5]*z[5]; s6 = z[6]*z[6]; s7 = z[7]*z[7];
#pragma unroll
    for (int i = 8; i < 64; i += 8) {
        s0 += z[i+0]*z[i+0]; s1 += z[i+1]*z[i+1];
        s2 += z[i+2]*z[i+2]; s3 += z[i+3]*z[i+3];
        s4 += z[i+4]*z[i+4]; s5 += z[i+5]*z[i+5];
        s6 += z[i+6]*z[i+6]; s7 += z[i+7]*z[i+7];
    }
    sum_rr = ((s0 + s1) + (s2 + s3)) + ((s4 + s5) + (s6 + s7));

    // ======== codebook 1 ========
    const float4* p14 = reinterpret_cast<const float4*>(ws + WS_P1);
    float best1 = 3.4e38f; int i1 = 0;
    for (int h = 0; h < 2; ++h) {
        __syncthreads();
#pragma unroll
        for (int i = 0; i < 4; ++i) sw4[i*256 + tid] = p14[h*1024 + i*256 + tid];
        __syncthreads();

        for (int q = 0; q < 4; ++q) {
            const float4* pan = sl4 + q*256;
            v2f av[8];
#pragma unroll
            for (int t = 0; t < 8; ++t) av[t] = (v2f){0.f, 0.f};
#pragma unroll
            for (int d = 0; d < DIM; ++d) {
                V2P P0 = __builtin_bit_cast(V2P, pan[d*4 + 0]);
                V2P P1 = __builtin_bit_cast(V2P, pan[d*4 + 1]);
                V2P P2 = __builtin_bit_cast(V2P, pan[d*4 + 2]);
                V2P P3 = __builtin_bit_cast(V2P, pan[d*4 + 3]);
                float zd = z[d];
                v2f zd2 = (v2f){zd, zd};
                PKF(av[0], P0.lo, zd2); PKF(av[1], P0.hi, zd2);
                PKF(av[2], P1.lo, zd2); PKF(av[3], P1.hi, zd2);
                PKF(av[4], P2.lo, zd2); PKF(av[5], P2.hi, zd2);
                PKF(av[6], P3.lo, zd2); PKF(av[7], P3.hi, zd2);
            }
            const int kb = h*64 + q*16;
            const float* nk = n1g + kb;
#pragma unroll
            for (int j = 0; j < 8; ++j) {
                float d0 = (sum_rr - 2.0f*av[j].x) + nk[2*j + 0];
                float d1 = (sum_rr - 2.0f*av[j].y) + nk[2*j + 1];
                if (d0 < best1) { best1 = d0; i1 = kb + 2*j + 0; }
                if (d1 < best1) { best1 = d1; i1 = kb + 2*j + 1; }
            }
        }
    }

    // ---- decode: out = T0[i0] + T1[i1] + b_out ----
    const float4* t0r = reinterpret_cast<const float4*>(T0 + (size_t)i0 * MEL_BINS);
    const float4* t1r = reinterpret_cast<const float4*>(T1 + (size_t)i1 * MEL_BINS);
    float4* outr = reinterpret_cast<float4*>(out_mel + (size_t)b * MEL_BINS);
#pragma unroll 4
    for (int q = 0; q < MEL_BINS / 4; ++q) {
        float4 a = t0r[q], cc = t1r[q];
        float4 o;
        o.x = a.x + cc.x + b_out[4*q + 0];
        o.y = a.y + cc.y + b_out[4*q + 1];
        o.z = a.z + cc.z + b_out[4*q + 2];
        o.w = a.w + cc.w + b_out[4*q + 3];
        outr[q] = o;
    }

    out_idx[2*(size_t)b + 0] = (float)i0;
    out_idx[2*(size_t)b + 1] = (float)i1;
}

extern "C" void kernel_launch(void* const* d_in, const int* in_sizes, int n_in,
                              void* d_out, int out_size, void* d_ws, size_t ws_size,
                              hipStream_t stream)
{
    const float* mel   = (const float*)d_in[0];
    const float* W_in  = (const float*)d_in[1];
    const float* b_in  = (const float*)d_in[2];
    const float* cb0   = (const float*)d_in[3];
    const float* cb1   = (const float*)d_in[4];
    const float* W_out = (const float*)d_in[5];
    const float* b_out = (const float*)d_in[6];

    float* ws      = (float*)d_ws;                 // 230400 bytes used
    float* out_mel = (float*)d_out;
    float* out_idx = (float*)d_out + (size_t)B_ROWS * MEL_BINS;

    rvq_precomp<<<(WS_TOT + 255) / 256, 256, 0, stream>>>(W_in, cb0, cb1, W_out, ws);
    rvq_main<<<B_ROWS / 256, 256, 0, stream>>>(mel, b_in, cb0, cb1, b_out, ws,
                                               out_mel, out_idx);
}